// Round 7
// baseline (691.274 us; speedup 1.0000x reference)
//
#include <hip/hip_runtime.h>
#include <hip/hip_bf16.h>

// Fused windowed MHA (f32 I/O), round 6: 2-blocks/CU edition.
// One block per window (B=2048), 512 threads = 8 waves, 6 groups x 2 heads.
// LDS 78 KB (xn + q/k (att overlay) + vT) -> 2 independent blocks/CU.
// pbuf eliminated: swapped QK^T (S^T = mfma(K,Q)) keeps P lane-local;
// softmax reduce = 2 shfl_xor; P normalized in-reg, packed bf16, redistributed
// into PV A-frags via 16 shfl + selects. att overlays q region (barrier C).

#define NTOK  64
#define CCH   384
#define NH    12
#define HD    32
#define EPSV  1e-5f
#define SCALEQ 0.17677669529663687f   // 1/sqrt(32)

#define XN_STRIDE  392   // shorts; 784B: 16B-aligned rows, 2-way banks
#define QK_STRIDE  40    // shorts; 80B rows
#define VT_STRIDE  72    // shorts; 144B rows
#define ATT_STRIDE 72    // shorts; overlays q region (64*72 <= 2*64*40)

#define WQKV_ELEMS (1152 * 384)
#define WOUT_ELEMS (384 * 384)
#define BLUT_ELEMS (NH * 64 * 64)

typedef __attribute__((ext_vector_type(8))) short  short8;
typedef __attribute__((ext_vector_type(4))) short  short4v;
typedef __attribute__((ext_vector_type(4))) float  float4v;
typedef __attribute__((ext_vector_type(4))) int    int4v;

__device__ __forceinline__ unsigned short f2bf(float f) {
    union { float f; unsigned int i; } v; v.f = f;
    unsigned int r = v.i + 0x7fffu + ((v.i >> 16) & 1u);   // RNE
    return (unsigned short)(r >> 16);
}
__device__ __forceinline__ unsigned int pack2bf(float lo, float hi) {
    return (unsigned int)f2bf(lo) | ((unsigned int)f2bf(hi) << 16);
}

__global__ void prep_kernel(const float* __restrict__ w_qkv_f,
                            const float* __restrict__ w_out_f,
                            const float* __restrict__ bias_tab,
                            const int*   __restrict__ rel_idx,
                            unsigned short* __restrict__ wq_bf,
                            unsigned short* __restrict__ wo_bf,
                            float* __restrict__ blut) {
    const int stride = gridDim.x * blockDim.x;
    const int tid = blockIdx.x * blockDim.x + threadIdx.x;
    for (int i = tid; i < WQKV_ELEMS; i += stride) wq_bf[i] = f2bf(w_qkv_f[i]);
    for (int i = tid; i < WOUT_ELEMS; i += stride) wo_bf[i] = f2bf(w_out_f[i]);
    for (int i = tid; i < BLUT_ELEMS; i += stride) {
        const int h = i >> 12, nm = i & 4095;              // blut[h][n][m]
        blut[i] = bias_tab[rel_idx[nm] * NH + h];
    }
}

__global__ __launch_bounds__(512, 4)
void fused_win_mha(const float* __restrict__ x,
                   const float* __restrict__ ln_g,
                   const float* __restrict__ ln_b,
                   const float* __restrict__ b_out,
                   const unsigned short* __restrict__ w_qkv,   // bf16 [1152][384]
                   const unsigned short* __restrict__ w_out,   // bf16 [384][384]
                   const float* __restrict__ blut,             // f32 [12][64][64]
                   float* __restrict__ out)                    // f32 [B][64][384]
{
    const int b    = blockIdx.x;
    const int t    = threadIdx.x;
    const int wav  = t >> 6;        // 0..7
    const int lane = t & 63;
    const int l4   = lane >> 4;     // 0..3
    const int lc   = lane & 15;     // 0..15
    // attention role
    const int hd   = wav >> 2;      // 0..1 head-local
    const int rt   = wav & 3;       // 0..3 token row-tile
    // GEMM1 role: waves 0-3 -> mts {0,1}, waves 4-7 -> {2,3}; nt base 3*(wav&3)
    const int g1m  = wav >> 2;
    const int g1n  = 3 * (wav & 3);
    // GEMM2 / epilogue role
    const int mh   = wav & 1;       // m-half (2 m-tiles)
    const int nq   = wav >> 1;      // 0..3 (6 n-tiles each)

    __shared__ unsigned short xn[NTOK][XN_STRIDE];                  // 50176 B
    __shared__ unsigned short qkreg[2 * 2 * NTOK * QK_STRIDE];      // 20480 B: q[2][64][40], k[2][64][40]; att overlays q
    __shared__ unsigned short vT[2][HD][VT_STRIDE];                 // 9216 B
    // total 79872 B -> 2 blocks/CU

#define QBUF(h, r, c)  qkreg[((h) * NTOK + (r)) * QK_STRIDE + (c)]
#define KBUF(h, r, c)  qkreg[2 * NTOK * QK_STRIDE + ((h) * NTOK + (r)) * QK_STRIDE + (c)]
#define ATT(r, c)      qkreg[(r) * ATT_STRIDE + (c)]

    // ---------------- LayerNorm (f32 x -> bf16 xn) ----------------
    {
        const int row = t >> 3, seg = t & 7;              // 8 threads per token row
        const float* xr = x + (b * NTOK + row) * CCH + seg * 48;
        float vals[48];
        float s = 0.f, s2 = 0.f;
        #pragma unroll
        for (int i = 0; i < 12; ++i) {
            float4v v = *(const float4v*)(xr + i * 4);
            #pragma unroll
            for (int j = 0; j < 4; ++j) {
                float f = v[j];
                vals[i * 4 + j] = f; s += f; s2 += f * f;
            }
        }
        s += __shfl_xor(s, 1); s2 += __shfl_xor(s2, 1);
        s += __shfl_xor(s, 2); s2 += __shfl_xor(s2, 2);
        s += __shfl_xor(s, 4); s2 += __shfl_xor(s2, 4);
        const float mu   = s * (1.f / CCH);
        const float rstd = rsqrtf(s2 * (1.f / CCH) - mu * mu + EPSV);
        #pragma unroll
        for (int i = 0; i < 12; ++i) {
            float4v gv = *(const float4v*)(ln_g + seg * 48 + i * 4);
            float4v bv = *(const float4v*)(ln_b + seg * 48 + i * 4);
            #pragma unroll
            for (int j = 0; j < 4; ++j)
                xn[row][seg * 48 + i * 4 + j] = f2bf((vals[i * 4 + j] - mu) * rstd * gv[j] + bv[j]);
        }
    }
    __syncthreads();

    // persistent GEMM2 accumulators: rows 16*(2mh+mtl), cols 16*(6nq+j2)+lc
    float4v facc[2][6];
    #pragma unroll
    for (int mtl = 0; mtl < 2; ++mtl)
        #pragma unroll
        for (int j = 0; j < 6; ++j)
            facc[mtl][j] = (float4v){0.f, 0.f, 0.f, 0.f};

    for (int grp = 0; grp < 6; ++grp) {
        // ---------------- GEMM1: qkv for heads {2g, 2g+1} ----------------
        // nt 0..11 = [head][q0,q1,k0,k1,v0,v1]; wave: nts {g1n..g1n+2}, mts {2g1m, 2g1m+1}
        float4v acc[3][2];
        #pragma unroll
        for (int n = 0; n < 3; ++n)
            #pragma unroll
            for (int m = 0; m < 2; ++m)
                acc[n][m] = (float4v){0.f, 0.f, 0.f, 0.f};

        int eRow[3], hd2_[3], mat_[3], half_[3];
        #pragma unroll
        for (int ntl = 0; ntl < 3; ++ntl) {
            const int nt = g1n + ntl;
            const int h2 = nt / 6, part = nt % 6;
            hd2_[ntl] = h2; mat_[ntl] = part >> 1; half_[ntl] = part & 1;
            eRow[ntl] = mat_[ntl] * CCH + (2 * grp + h2) * HD + half_[ntl] * 16 + lc;
        }
        for (int kk = 0; kk < 12; ++kk) {
            short8 aF[2];
            #pragma unroll
            for (int mtl = 0; mtl < 2; ++mtl)
                aF[mtl] = *(const short8*)&xn[16 * (2 * g1m + mtl) + lc][32 * kk + 8 * l4];
            #pragma unroll
            for (int ntl = 0; ntl < 3; ++ntl) {
                short8 bF = *(const short8*)(w_qkv + eRow[ntl] * CCH + 32 * kk + 8 * l4);
                #pragma unroll
                for (int mtl = 0; mtl < 2; ++mtl)
                    acc[ntl][mtl] = __builtin_amdgcn_mfma_f32_16x16x32_bf16(aF[mtl], bF, acc[ntl][mtl], 0, 0, 0);
            }
        }
        __syncthreads();   // barrier A: prev GEMM2 att-reads (q region) done; prev QK/PV LDS reads done

        // ---------------- scatter q(scaled), k, vT ----------------
        #pragma unroll
        for (int ntl = 0; ntl < 3; ++ntl) {
            const int h2 = hd2_[ntl], mat = mat_[ntl], half = half_[ntl];
            #pragma unroll
            for (int mtl = 0; mtl < 2; ++mtl) {
                const int mt = 2 * g1m + mtl;
                if (mat == 0) {
                    #pragma unroll
                    for (int r = 0; r < 4; ++r)
                        QBUF(h2, 16 * mt + 4 * l4 + r, half * 16 + lc) = f2bf(acc[ntl][mtl][r] * SCALEQ);
                } else if (mat == 1) {
                    #pragma unroll
                    for (int r = 0; r < 4; ++r)
                        KBUF(h2, 16 * mt + 4 * l4 + r, half * 16 + lc) = f2bf(acc[ntl][mtl][r]);
                } else {
                    short4v pk4;
                    #pragma unroll
                    for (int r = 0; r < 4; ++r)
                        pk4[r] = (short)f2bf(acc[ntl][mtl][r]);
                    *(short4v*)&vT[h2][half * 16 + lc][16 * mt + 4 * l4] = pk4;  // ds_write_b64
                }
            }
        }
        __syncthreads();   // barrier B: q,k,vT visible

        // ---------------- swapped QK^T + bias + softmax (head hd, tokens 16rt..+15) ----------------
        // S^T = mfma(A=k, B=q): lane (lc,l4) gets S[token 16rt+lc][key 16kt+4l4+r]
        float sv[4][4];
        {
            short8 qf = *(const short8*)&QBUF(hd, 16 * rt + lc, 8 * l4);
            #pragma unroll
            for (int kt = 0; kt < 4; ++kt) {
                short8 kf = *(const short8*)&KBUF(hd, 16 * kt + lc, 8 * l4);
                float4v sres = __builtin_amdgcn_mfma_f32_16x16x32_bf16(
                    kf, qf, (float4v){0.f, 0.f, 0.f, 0.f}, 0, 0, 0);
                #pragma unroll
                for (int r = 0; r < 4; ++r) sv[kt][r] = sres[r];
            }
        }
        {
            const float* bl = blut + (2 * grp + hd) * 4096 + (16 * rt + lc) * 64;
            float m = -1e30f;
            #pragma unroll
            for (int kt = 0; kt < 4; ++kt) {
                float4v bb = *(const float4v*)(bl + 16 * kt + 4 * l4);
                #pragma unroll
                for (int r = 0; r < 4; ++r) {
                    sv[kt][r] += bb[r];
                    m = fmaxf(m, sv[kt][r]);
                }
            }
            m = fmaxf(m, __shfl_xor(m, 16));
            m = fmaxf(m, __shfl_xor(m, 32));
            float s = 0.f;
            #pragma unroll
            for (int kt = 0; kt < 4; ++kt)
                #pragma unroll
                for (int r = 0; r < 4; ++r) {
                    float pe = __expf(sv[kt][r] - m);
                    sv[kt][r] = pe; s += pe;
                }
            s += __shfl_xor(s, 16);
            s += __shfl_xor(s, 32);
            const float rinv = 1.f / s;
            #pragma unroll
            for (int kt = 0; kt < 4; ++kt)
                #pragma unroll
                for (int r = 0; r < 4; ++r)
                    sv[kt][r] *= rinv;   // normalized P
        }
        // pack P to bf16 pairs: pk2[kt][0] = keys {16kt+4l4+0,1}, [1] = {+2,+3}
        unsigned int pk2[4][2];
        #pragma unroll
        for (int kt = 0; kt < 4; ++kt) {
            pk2[kt][0] = pack2bf(sv[kt][0], sv[kt][1]);
            pk2[kt][1] = pack2bf(sv[kt][2], sv[kt][3]);
        }
        // redistribute into PV A-frags: lane (lc,l4) needs P[token lc][keys 32kk2+8l4..+7]
        short8 af[2];
        {
            const int src0 = lc + 16 * (2 * (l4 & 1));
            const int src1 = src0 + 16;
            const bool hi  = ((l4 >> 1) & 1) != 0;
            #pragma unroll
            for (int kk2 = 0; kk2 < 2; ++kk2) {
                const int ka = 2 * kk2, kb = 2 * kk2 + 1;
                unsigned int a0a = (unsigned int)__shfl((int)pk2[ka][0], src0);
                unsigned int a0b = (unsigned int)__shfl((int)pk2[kb][0], src0);
                unsigned int a1a = (unsigned int)__shfl((int)pk2[ka][1], src0);
                unsigned int a1b = (unsigned int)__shfl((int)pk2[kb][1], src0);
                unsigned int a2a = (unsigned int)__shfl((int)pk2[ka][0], src1);
                unsigned int a2b = (unsigned int)__shfl((int)pk2[kb][0], src1);
                unsigned int a3a = (unsigned int)__shfl((int)pk2[ka][1], src1);
                unsigned int a3b = (unsigned int)__shfl((int)pk2[kb][1], src1);
                int4v iv;
                iv[0] = (int)(hi ? a0b : a0a);
                iv[1] = (int)(hi ? a1b : a1a);
                iv[2] = (int)(hi ? a2b : a2a);
                iv[3] = (int)(hi ? a3b : a3a);
                af[kk2] = __builtin_bit_cast(short8, iv);
            }
        }
        __syncthreads();   // barrier C: all q/k LDS reads done (att will overlay q region)

        // ---------------- PV (tokens 16rt..+15, head hd) ----------------
        float4v o[2];
        o[0] = (float4v){0.f, 0.f, 0.f, 0.f};
        o[1] = (float4v){0.f, 0.f, 0.f, 0.f};
        #pragma unroll
        for (int kk2 = 0; kk2 < 2; ++kk2) {
            #pragma unroll
            for (int nt = 0; nt < 2; ++nt) {
                short8 vf = *(const short8*)&vT[hd][16 * nt + lc][32 * kk2 + 8 * l4];
                o[nt] = __builtin_amdgcn_mfma_f32_16x16x32_bf16(af[kk2], vf, o[nt], 0, 0, 0);
            }
        }
        // att (already normalized) -> overlay on q region
        #pragma unroll
        for (int nt = 0; nt < 2; ++nt)
            #pragma unroll
            for (int r = 0; r < 4; ++r)
                ATT(16 * rt + 4 * l4 + r, 32 * hd + 16 * nt + lc) = f2bf(o[nt][r]);
        __syncthreads();   // barrier D: att visible

        // ---------------- GEMM2 partial: facc += att @ w_out[:, 64g..64g+63]^T ----------------
        #pragma unroll
        for (int ks = 0; ks < 2; ++ks) {
            short8 aG[2];
            #pragma unroll
            for (int mtl = 0; mtl < 2; ++mtl)
                aG[mtl] = *(const short8*)&ATT(16 * (2 * mh + mtl) + lc, 32 * ks + 8 * l4);
            #pragma unroll
            for (int j2 = 0; j2 < 6; ++j2) {
                const int c = 16 * (6 * nq + j2) + lc;
                short8 bG = *(const short8*)(w_out + c * CCH + 64 * grp + 32 * ks + 8 * l4);
                #pragma unroll
                for (int mtl = 0; mtl < 2; ++mtl)
                    facc[mtl][j2] = __builtin_amdgcn_mfma_f32_16x16x32_bf16(aG[mtl], bG, facc[mtl][j2], 0, 0, 0);
            }
        }
        // no barrier: next GEMM1 reads only xn/global; barrier A precedes next scatter
    }

    // ---------------- epilogue: facc + b_out -> direct f32 global stores ----------------
    {
        float* ob = out + b * (NTOK * CCH);
        #pragma unroll
        for (int mtl = 0; mtl < 2; ++mtl) {
            #pragma unroll
            for (int j2 = 0; j2 < 6; ++j2) {
                const int c = 16 * (6 * nq + j2) + lc;
                const float bo = b_out[c];
                #pragma unroll
                for (int r = 0; r < 4; ++r)
                    ob[(16 * (2 * mh + mtl) + 4 * l4 + r) * CCH + c] = facc[mtl][j2][r] + bo;
            }
        }
    }
#undef QBUF
#undef KBUF
#undef ATT
}

extern "C" void kernel_launch(void* const* d_in, const int* in_sizes, int n_in,
                              void* d_out, int out_size, void* d_ws, size_t ws_size,
                              hipStream_t stream) {
    const float* x     = (const float*)d_in[0];
    const float* ln_g  = (const float*)d_in[1];
    const float* ln_b  = (const float*)d_in[2];
    const float* w_qkv = (const float*)d_in[3];
    const float* w_out = (const float*)d_in[4];
    const float* b_out = (const float*)d_in[5];
    const float* btab  = (const float*)d_in[6];
    const int*   ridx  = (const int*)d_in[7];
    float*       out   = (float*)d_out;

    unsigned short* wq_bf = (unsigned short*)d_ws;
    unsigned short* wo_bf = wq_bf + WQKV_ELEMS;
    float*          blut  = (float*)(wo_bf + WOUT_ELEMS);   // byte offset 1179648, 16B-aligned

    prep_kernel<<<512, 256, 0, stream>>>(w_qkv, w_out, btab, ridx, wq_bf, wo_bf, blut);
    fused_win_mha<<<2048, 512, 0, stream>>>(x, ln_g, ln_b, b_out, wq_bf, wo_bf, blut, out);
}

// Round 8
// 357.461 us; speedup vs baseline: 1.9338x; 1.9338x over previous
//
#include <hip/hip_runtime.h>
#include <hip/hip_bf16.h>

// Round 8: r4 structure (best measured: 468us) + coalesced fragment-major weight
// layouts + in-register P (r7-validated). One block per window, 512 thr = 8 waves,
// 3 groups x 4 heads, 1 block/CU (107 KB LDS), launch_bounds(512,2).
// prep packs: wqp[72][12][64][8] bf16, wop[24][12][64][8] bf16, blutp[12][4][4][64][4] f32
// so every weight/bias load is a contiguous 1KB-per-wave coalesced load.

#define NTOK  64
#define CCH   384
#define NH    12
#define HD    32
#define EPSV  1e-5f
#define SCALEQ 0.17677669529663687f   // 1/sqrt(32)

#define XN_STRIDE  392   // shorts (784B rows)
#define QK_STRIDE  40    // shorts (80B rows)
#define VT_STRIDE  72    // shorts (144B rows)
#define ATT_STRIDE 136   // shorts (272B rows), overlays q region

#define WQP_ELEMS (72 * 12 * 64 * 8)    // 442368 = 1152*384
#define WOP_ELEMS (24 * 12 * 64 * 8)    // 147456 = 384*384
#define BLUTP_ELEMS (12 * 4 * 4 * 64 * 4) // 196608 f32

typedef __attribute__((ext_vector_type(8))) short  short8;
typedef __attribute__((ext_vector_type(4))) short  short4v;
typedef __attribute__((ext_vector_type(4))) float  float4v;
typedef __attribute__((ext_vector_type(4))) int    int4v;

__device__ __forceinline__ unsigned short f2bf(float f) {
    union { float f; unsigned int i; } v; v.f = f;
    unsigned int r = v.i + 0x7fffu + ((v.i >> 16) & 1u);   // RNE
    return (unsigned short)(r >> 16);
}
__device__ __forceinline__ unsigned int pack2bf(float lo, float hi) {
    return (unsigned int)f2bf(lo) | ((unsigned int)f2bf(hi) << 16);
}

__global__ void prep_kernel(const float* __restrict__ w_qkv_f,
                            const float* __restrict__ w_out_f,
                            const float* __restrict__ bias_tab,
                            const int*   __restrict__ rel_idx,
                            unsigned short* __restrict__ wqp,
                            unsigned short* __restrict__ wop,
                            float* __restrict__ blutp) {
    const int stride = gridDim.x * blockDim.x;
    const int tid = blockIdx.x * blockDim.x + threadIdx.x;
    // wqp[t][kk][lane][e] = w_qkv[16t + (lane&15)][32kk + 8*(lane>>4) + e]
    for (int i = tid; i < WQP_ELEMS; i += stride) {
        const int t = i / 6144, rem = i % 6144;
        const int kk = rem >> 9, rem2 = rem & 511;
        const int lane = rem2 >> 3, e = rem2 & 7;
        wqp[i] = f2bf(w_qkv_f[(16 * t + (lane & 15)) * CCH + 32 * kk + 8 * (lane >> 4) + e]);
    }
    // wop[t][kk][lane][e] = w_out[16t + (lane&15)][32kk + 8*(lane>>4) + e]
    for (int i = tid; i < WOP_ELEMS; i += stride) {
        const int t = i / 6144, rem = i % 6144;
        const int kk = rem >> 9, rem2 = rem & 511;
        const int lane = rem2 >> 3, e = rem2 & 7;
        wop[i] = f2bf(w_out_f[(16 * t + (lane & 15)) * CCH + 32 * kk + 8 * (lane >> 4) + e]);
    }
    // blutp[h][tt][kt][lane][r] = bias[token=16tt+(lane&15)][key=16kt+4*(lane>>4)+r] of head h
    for (int i = tid; i < BLUTP_ELEMS; i += stride) {
        const int r = i & 3, lane = (i >> 2) & 63;
        const int kt = (i >> 8) & 3, tt = (i >> 10) & 3, h = i >> 12;
        const int token = 16 * tt + (lane & 15);
        const int key   = 16 * kt + 4 * (lane >> 4) + r;
        blutp[i] = bias_tab[rel_idx[token * 64 + key] * NH + h];
    }
}

__global__ __launch_bounds__(512, 2)
void fused_win_mha(const float* __restrict__ x,
                   const float* __restrict__ ln_g,
                   const float* __restrict__ ln_b,
                   const float* __restrict__ b_out,
                   const unsigned short* __restrict__ wqp,
                   const unsigned short* __restrict__ wop,
                   const float* __restrict__ blutp,
                   float* __restrict__ out)
{
    const int b    = blockIdx.x;
    const int t    = threadIdx.x;
    const int wav  = t >> 6;        // 0..7
    const int lane = t & 63;
    const int l4   = lane >> 4;     // 0..3
    const int lc   = lane & 15;     // 0..15
    const int lh   = wav >> 1;      // 0..3 head-local (attention)
    const int mh   = wav & 1;       // 0..1 m-half

    __shared__ unsigned short xn[NTOK][XN_STRIDE];        // 50176 B
    __shared__ unsigned short qk[2 * 4 * NTOK * QK_STRIDE]; // 40960 B: q[4][64][40], k[4][64][40]; ATT overlays q
    __shared__ unsigned short vT[4][HD][VT_STRIDE];       // 18432 B
    // total 109568 B -> 1 block/CU

#define QBUF(h, r, c)  qk[((h) * NTOK + (r)) * QK_STRIDE + (c)]
#define KBUF(h, r, c)  qk[4 * NTOK * QK_STRIDE + ((h) * NTOK + (r)) * QK_STRIDE + (c)]
#define ATT(r, c)      qk[(r) * ATT_STRIDE + (c)]          // 64x136 <= q region (4*64*40)

    // ---------------- LayerNorm (f32 x -> bf16 xn) ----------------
    {
        const int row = t >> 3, seg = t & 7;
        const float* xr = x + (b * NTOK + row) * CCH + seg * 48;
        float vals[48];
        float s = 0.f, s2 = 0.f;
        #pragma unroll
        for (int i = 0; i < 12; ++i) {
            float4v v = *(const float4v*)(xr + i * 4);
            #pragma unroll
            for (int j = 0; j < 4; ++j) {
                float f = v[j];
                vals[i * 4 + j] = f; s += f; s2 += f * f;
            }
        }
        s += __shfl_xor(s, 1); s2 += __shfl_xor(s2, 1);
        s += __shfl_xor(s, 2); s2 += __shfl_xor(s2, 2);
        s += __shfl_xor(s, 4); s2 += __shfl_xor(s2, 4);
        const float mu   = s * (1.f / CCH);
        const float rstd = rsqrtf(s2 * (1.f / CCH) - mu * mu + EPSV);
        #pragma unroll
        for (int i = 0; i < 12; ++i) {
            float4v gv = *(const float4v*)(ln_g + seg * 48 + i * 4);
            float4v bv = *(const float4v*)(ln_b + seg * 48 + i * 4);
            #pragma unroll
            for (int j = 0; j < 4; ++j)
                xn[row][seg * 48 + i * 4 + j] = f2bf((vals[i * 4 + j] - mu) * rstd * gv[j] + bv[j]);
        }
    }
    __syncthreads();

    // persistent GEMM2 accumulators: rows 16mt+, cols 16*(3wav+j2)+lc
    float4v facc[4][3];
    #pragma unroll
    for (int mt = 0; mt < 4; ++mt)
        #pragma unroll
        for (int j = 0; j < 3; ++j)
            facc[mt][j] = (float4v){0.f, 0.f, 0.f, 0.f};

    for (int grp = 0; grp < 3; ++grp) {
        const int h = 4 * grp + lh;   // this wave's attention head

        // ---------------- GEMM1: qkv for heads 4g..4g+3 ----------------
        // wave (lh,mh): parts 3mh..3mh+2 of head lh's 6 (q0,q1,k0,k1,v0,v1); all 4 M-tiles
        float4v acc[3][4];
        #pragma unroll
        for (int n = 0; n < 3; ++n)
            #pragma unroll
            for (int m = 0; m < 4; ++m)
                acc[n][m] = (float4v){0.f, 0.f, 0.f, 0.f};

        int tile_[3], mat_[3], half_[3];
        #pragma unroll
        for (int ntl = 0; ntl < 3; ++ntl) {
            const int part = 3 * mh + ntl;
            mat_[ntl] = part >> 1; half_[ntl] = part & 1;
            tile_[ntl] = mat_[ntl] * 24 + h * 2 + half_[ntl];
        }
        for (int kk = 0; kk < 12; ++kk) {
            short8 aF[4];
            #pragma unroll
            for (int mt = 0; mt < 4; ++mt)
                aF[mt] = *(const short8*)&xn[16 * mt + lc][32 * kk + 8 * l4];
            #pragma unroll
            for (int ntl = 0; ntl < 3; ++ntl) {
                short8 bF = *(const short8*)&wqp[((tile_[ntl] * 12 + kk) << 9) + (lane << 3)];
                #pragma unroll
                for (int mt = 0; mt < 4; ++mt)
                    acc[ntl][mt] = __builtin_amdgcn_mfma_f32_16x16x32_bf16(aF[mt], bF, acc[ntl][mt], 0, 0, 0);
            }
        }
        __syncthreads();   // barrier A: prev GEMM2 ATT reads + prev PV vT reads done

        // ---------------- scatter q(scaled), k, vT ----------------
        #pragma unroll
        for (int ntl = 0; ntl < 3; ++ntl) {
            const int mat = mat_[ntl], half = half_[ntl];
            #pragma unroll
            for (int mt = 0; mt < 4; ++mt) {
                if (mat == 0) {
                    #pragma unroll
                    for (int r = 0; r < 4; ++r)
                        QBUF(lh, 16 * mt + 4 * l4 + r, half * 16 + lc) = f2bf(acc[ntl][mt][r] * SCALEQ);
                } else if (mat == 1) {
                    #pragma unroll
                    for (int r = 0; r < 4; ++r)
                        KBUF(lh, 16 * mt + 4 * l4 + r, half * 16 + lc) = f2bf(acc[ntl][mt][r]);
                } else {
                    short4v pk4;
                    #pragma unroll
                    for (int r = 0; r < 4; ++r)
                        pk4[r] = (short)f2bf(acc[ntl][mt][r]);
                    *(short4v*)&vT[lh][half * 16 + lc][16 * mt + 4 * l4] = pk4;
                }
            }
        }
        __syncthreads();   // barrier B: q,k,vT visible

        // ---------------- swapped QK^T + bias + softmax (head h, token-tiles 2mh, 2mh+1) ----------------
        // S^T = mfma(A=kf, B=qf): lane(lc,l4) reg r = S[token 16tt+lc][key 16kt+4l4+r]
        float sv[2][4][4];
        #pragma unroll
        for (int j = 0; j < 2; ++j) {
            short8 qf = *(const short8*)&QBUF(lh, 16 * (2 * mh + j) + lc, 8 * l4);
            #pragma unroll
            for (int kt = 0; kt < 4; ++kt) {
                short8 kf = *(const short8*)&KBUF(lh, 16 * kt + lc, 8 * l4);
                float4v sres = __builtin_amdgcn_mfma_f32_16x16x32_bf16(
                    kf, qf, (float4v){0.f, 0.f, 0.f, 0.f}, 0, 0, 0);
                #pragma unroll
                for (int r = 0; r < 4; ++r) sv[j][kt][r] = sres[r];
            }
        }
        unsigned int pk2[2][4][2];
        #pragma unroll
        for (int j = 0; j < 2; ++j) {
            const int tt = 2 * mh + j;
            float m = -1e30f;
            #pragma unroll
            for (int kt = 0; kt < 4; ++kt) {
                const float4v bb = *(const float4v*)(blutp + ((((h * 4 + tt) * 4 + kt) << 6) + lane) * 4);
                #pragma unroll
                for (int r = 0; r < 4; ++r) {
                    sv[j][kt][r] += bb[r];
                    m = fmaxf(m, sv[j][kt][r]);
                }
            }
            m = fmaxf(m, __shfl_xor(m, 16));
            m = fmaxf(m, __shfl_xor(m, 32));
            float s = 0.f;
            #pragma unroll
            for (int kt = 0; kt < 4; ++kt)
                #pragma unroll
                for (int r = 0; r < 4; ++r) {
                    float pe = __expf(sv[j][kt][r] - m);
                    sv[j][kt][r] = pe; s += pe;
                }
            s += __shfl_xor(s, 16);
            s += __shfl_xor(s, 32);
            const float rinv = 1.f / s;
            #pragma unroll
            for (int kt = 0; kt < 4; ++kt) {
                pk2[j][kt][0] = pack2bf(sv[j][kt][0] * rinv, sv[j][kt][1] * rinv);
                pk2[j][kt][1] = pack2bf(sv[j][kt][2] * rinv, sv[j][kt][3] * rinv);
            }
        }
        // redistribute into PV A-frags: lane(lc,l4) needs P[token 16tt+lc][keys 32kk2+8l4..+7]
        short8 af[2][2];
        {
            const int src0 = lc + 16 * (2 * (l4 & 1));
            const int src1 = src0 + 16;
            const bool hi  = ((l4 >> 1) & 1) != 0;
            #pragma unroll
            for (int j = 0; j < 2; ++j) {
                #pragma unroll
                for (int kk2 = 0; kk2 < 2; ++kk2) {
                    const int ka = 2 * kk2, kb = 2 * kk2 + 1;
                    unsigned int a0a = (unsigned int)__shfl((int)pk2[j][ka][0], src0);
                    unsigned int a0b = (unsigned int)__shfl((int)pk2[j][kb][0], src0);
                    unsigned int a1a = (unsigned int)__shfl((int)pk2[j][ka][1], src0);
                    unsigned int a1b = (unsigned int)__shfl((int)pk2[j][kb][1], src0);
                    unsigned int a2a = (unsigned int)__shfl((int)pk2[j][ka][0], src1);
                    unsigned int a2b = (unsigned int)__shfl((int)pk2[j][kb][0], src1);
                    unsigned int a3a = (unsigned int)__shfl((int)pk2[j][ka][1], src1);
                    unsigned int a3b = (unsigned int)__shfl((int)pk2[j][kb][1], src1);
                    int4v iv;
                    iv[0] = (int)(hi ? a0b : a0a);
                    iv[1] = (int)(hi ? a1b : a1a);
                    iv[2] = (int)(hi ? a2b : a2a);
                    iv[3] = (int)(hi ? a3b : a3a);
                    af[j][kk2] = __builtin_bit_cast(short8, iv);
                }
            }
        }
        __syncthreads();   // barrier C: q/k LDS reads done; ATT may overlay q region

        // ---------------- PV (token-tiles 2mh..2mh+1, head h) ----------------
        float4v o[2][2];
        #pragma unroll
        for (int j = 0; j < 2; ++j)
            #pragma unroll
            for (int nt = 0; nt < 2; ++nt)
                o[j][nt] = (float4v){0.f, 0.f, 0.f, 0.f};
        #pragma unroll
        for (int kk2 = 0; kk2 < 2; ++kk2) {
            #pragma unroll
            for (int nt = 0; nt < 2; ++nt) {
                short8 vf = *(const short8*)&vT[lh][16 * nt + lc][32 * kk2 + 8 * l4];
                #pragma unroll
                for (int j = 0; j < 2; ++j)
                    o[j][nt] = __builtin_amdgcn_mfma_f32_16x16x32_bf16(af[j][kk2], vf, o[j][nt], 0, 0, 0);
            }
        }
        // att (normalized) -> ATT overlay, cols 32*lh + 16*nt + lc
        #pragma unroll
        for (int j = 0; j < 2; ++j)
            #pragma unroll
            for (int nt = 0; nt < 2; ++nt)
                #pragma unroll
                for (int r = 0; r < 4; ++r)
                    ATT(16 * (2 * mh + j) + 4 * l4 + r, 32 * lh + 16 * nt + lc) = f2bf(o[j][nt][r]);
        __syncthreads();   // barrier D: ATT visible

        // ---------------- GEMM2 partial: facc += ATT @ wout[:,128g..+127]^T ----------------
        #pragma unroll
        for (int ks = 0; ks < 4; ++ks) {
            short8 aG[4];
            #pragma unroll
            for (int mt = 0; mt < 4; ++mt)
                aG[mt] = *(const short8*)&ATT(16 * mt + lc, 32 * ks + 8 * l4);
            #pragma unroll
            for (int j2 = 0; j2 < 3; ++j2) {
                const int tile = 3 * wav + j2;
                short8 bG = *(const short8*)&wop[((tile * 12 + 4 * grp + ks) << 9) + (lane << 3)];
                #pragma unroll
                for (int mt = 0; mt < 4; ++mt)
                    facc[mt][j2] = __builtin_amdgcn_mfma_f32_16x16x32_bf16(aG[mt], bG, facc[mt][j2], 0, 0, 0);
            }
        }
        // no barrier: next GEMM1 reads only xn/global; barrier A precedes next scatter
    }

    // ---------------- epilogue: facc + b_out -> direct f32 global stores ----------------
    {
        float* ob = out + b * (NTOK * CCH);
        #pragma unroll
        for (int mt = 0; mt < 4; ++mt) {
            #pragma unroll
            for (int j2 = 0; j2 < 3; ++j2) {
                const int c = 16 * (3 * wav + j2) + lc;
                const float bo = b_out[c];
                #pragma unroll
                for (int r = 0; r < 4; ++r)
                    ob[(16 * mt + 4 * l4 + r) * CCH + c] = facc[mt][j2][r] + bo;
            }
        }
    }
#undef QBUF
#undef KBUF
#undef ATT
}

extern "C" void kernel_launch(void* const* d_in, const int* in_sizes, int n_in,
                              void* d_out, int out_size, void* d_ws, size_t ws_size,
                              hipStream_t stream) {
    const float* x     = (const float*)d_in[0];
    const float* ln_g  = (const float*)d_in[1];
    const float* ln_b  = (const float*)d_in[2];
    const float* w_qkv = (const float*)d_in[3];
    const float* w_out = (const float*)d_in[4];
    const float* b_out = (const float*)d_in[5];
    const float* btab  = (const float*)d_in[6];
    const int*   ridx  = (const int*)d_in[7];
    float*       out   = (float*)d_out;

    unsigned short* wqp   = (unsigned short*)d_ws;
    unsigned short* wop   = wqp + WQP_ELEMS;
    float*          blutp = (float*)(wop + WOP_ELEMS);   // byte offset 1179648, 16B-aligned

    prep_kernel<<<512, 256, 0, stream>>>(w_qkv, w_out, btab, ridx, wqp, wop, blutp);
    fused_win_mha<<<2048, 512, 0, stream>>>(x, ln_g, ln_b, b_out, wqp, wop, blutp, out);
}

// Round 9
// 342.290 us; speedup vs baseline: 2.0196x; 1.0443x over previous
//
#include <hip/hip_runtime.h>
#include <hip/hip_bf16.h>

// Round 9: r8 + fully packed (fragment-major) LDS layouts + 7-barrier schedule + bias prefetch.
// One block per window (B=2048), 512 thr = 8 waves, 3 groups x 4 heads, 1 block/CU.
// Every MFMA operand ds_read is base + lane*16 (conflict-free, m134 pattern).
// Barriers: LN + {B: post-scatter, D: post-ATT-write} x 3 = 7 total.
// Phase D->B fuses GEMM2(g-1) + GEMM1(g) + scatter(g) (~84 MFMA to hide latency).

#define NTOK  64
#define CCH   384
#define NH    12
#define HD    32
#define EPSV  1e-5f
#define SCALEQ 0.17677669529663687f   // 1/sqrt(32)

#define WQP_ELEMS (72 * 12 * 64 * 8)      // 442368 bf16
#define WOP_ELEMS (24 * 12 * 64 * 8)      // 147456 bf16
#define BLUTP_ELEMS (12 * 4 * 4 * 64 * 4) // 196608 f32

typedef __attribute__((ext_vector_type(8))) short  short8;
typedef __attribute__((ext_vector_type(4))) short  short4v;
typedef __attribute__((ext_vector_type(4))) float  float4v;
typedef __attribute__((ext_vector_type(4))) int    int4v;

__device__ __forceinline__ unsigned short f2bf(float f) {
    union { float f; unsigned int i; } v; v.f = f;
    unsigned int r = v.i + 0x7fffu + ((v.i >> 16) & 1u);   // RNE
    return (unsigned short)(r >> 16);
}
__device__ __forceinline__ unsigned int pack2bf(float lo, float hi) {
    return (unsigned int)f2bf(lo) | ((unsigned int)f2bf(hi) << 16);
}

__global__ void prep_kernel(const float* __restrict__ w_qkv_f,
                            const float* __restrict__ w_out_f,
                            const float* __restrict__ bias_tab,
                            const int*   __restrict__ rel_idx,
                            unsigned short* __restrict__ wqp,
                            unsigned short* __restrict__ wop,
                            float* __restrict__ blutp) {
    const int stride = gridDim.x * blockDim.x;
    const int tid = blockIdx.x * blockDim.x + threadIdx.x;
    // wqp[t][kk][lane][e] = w_qkv[16t + (lane&15)][32kk + 8*(lane>>4) + e]
    for (int i = tid; i < WQP_ELEMS; i += stride) {
        const int t = i / 6144, rem = i % 6144;
        const int kk = rem >> 9, rem2 = rem & 511;
        const int lane = rem2 >> 3, e = rem2 & 7;
        wqp[i] = f2bf(w_qkv_f[(16 * t + (lane & 15)) * CCH + 32 * kk + 8 * (lane >> 4) + e]);
    }
    // wop[t][kk][lane][e] = w_out[16t + (lane&15)][32kk + 8*(lane>>4) + e]
    for (int i = tid; i < WOP_ELEMS; i += stride) {
        const int t = i / 6144, rem = i % 6144;
        const int kk = rem >> 9, rem2 = rem & 511;
        const int lane = rem2 >> 3, e = rem2 & 7;
        wop[i] = f2bf(w_out_f[(16 * t + (lane & 15)) * CCH + 32 * kk + 8 * (lane >> 4) + e]);
    }
    // blutp[h][tt][kt][lane][r] = bias[token=16tt+(lane&15)][key=16kt+4*(lane>>4)+r] of head h
    for (int i = tid; i < BLUTP_ELEMS; i += stride) {
        const int r = i & 3, lane = (i >> 2) & 63;
        const int kt = (i >> 8) & 3, tt = (i >> 10) & 3, h = i >> 12;
        const int token = 16 * tt + (lane & 15);
        const int key   = 16 * kt + 4 * (lane >> 4) + r;
        blutp[i] = bias_tab[rel_idx[token * 64 + key] * NH + h];
    }
}

__global__ __launch_bounds__(512, 2)
void fused_win_mha(const float* __restrict__ x,
                   const float* __restrict__ ln_g,
                   const float* __restrict__ ln_b,
                   const float* __restrict__ b_out,
                   const unsigned short* __restrict__ wqp,
                   const unsigned short* __restrict__ wop,
                   const float* __restrict__ blutp,
                   float* __restrict__ out)
{
    const int b    = blockIdx.x;
    const int t    = threadIdx.x;
    const int wav  = t >> 6;        // 0..7
    const int lane = t & 63;
    const int l4   = lane >> 4;     // 0..3
    const int lc   = lane & 15;     // 0..15
    const int lh   = wav >> 1;      // 0..3 head-local
    const int mh   = wav & 1;       // 0..1 m-half / token-half

    // packed fragment-major LDS: all reads are base + lane*16B (conflict-free)
    __shared__ unsigned short xnp[4 * 12 * 64 * 8];   // 49152 B  A-frags of xn: [mt][kk][lane][8]
    __shared__ unsigned short qp [4 * 4 * 64 * 8];    // 16384 B  B-frags of q:  [head][tt][lane][8]
    __shared__ unsigned short kp [4 * 4 * 64 * 8];    // 16384 B  A-frags of k:  [head][kt][lane][8]
    __shared__ unsigned short vp [4 * 2 * 2 * 64 * 8];// 16384 B  B-frags of v:  [head][nt][kk2][lane][8]
    __shared__ unsigned short attp[4 * 4 * 64 * 8];   // 16384 B  A-frags of att:[mt][ks][lane][8]
    // total 114688 B -> 1 block/CU

    // ---------------- LayerNorm (f32 x -> bf16 xnp, packed) ----------------
    {
        const int row = t >> 3, seg = t & 7;
        const float* xr = x + (b * NTOK + row) * CCH + seg * 48;
        float vals[48];
        float s = 0.f, s2 = 0.f;
        #pragma unroll
        for (int i = 0; i < 12; ++i) {
            float4v v = *(const float4v*)(xr + i * 4);
            #pragma unroll
            for (int j = 0; j < 4; ++j) {
                float f = v[j];
                vals[i * 4 + j] = f; s += f; s2 += f * f;
            }
        }
        s += __shfl_xor(s, 1); s2 += __shfl_xor(s2, 1);
        s += __shfl_xor(s, 2); s2 += __shfl_xor(s2, 2);
        s += __shfl_xor(s, 4); s2 += __shfl_xor(s2, 4);
        const float mu   = s * (1.f / CCH);
        const float rstd = rsqrtf(s2 * (1.f / CCH) - mu * mu + EPSV);
        #pragma unroll
        for (int u = 0; u < 6; ++u) {
            const int col0 = seg * 48 + u * 8;
            short8 w;
            #pragma unroll
            for (int e2 = 0; e2 < 2; ++e2) {
                float4v gv = *(const float4v*)(ln_g + col0 + e2 * 4);
                float4v bv = *(const float4v*)(ln_b + col0 + e2 * 4);
                #pragma unroll
                for (int j = 0; j < 4; ++j)
                    w[e2 * 4 + j] = (short)f2bf((vals[u * 8 + e2 * 4 + j] - mu) * rstd * gv[j] + bv[j]);
            }
            // xnp[mt=row>>4][kk=col0>>5][lane'=((col0>>3)&3)*16 + (row&15)][e]
            const int idx = ((((row >> 4) * 12 + (col0 >> 5)) << 9)
                             + ((((col0 >> 3) & 3) * 16 + (row & 15)) << 3));
            *(short8*)&xnp[idx] = w;
        }
    }
    __syncthreads();

    // persistent GEMM2 accumulators: rows 16mt+, cols 16*(3wav+j2)+lc
    float4v facc[4][3];
    #pragma unroll
    for (int mt = 0; mt < 4; ++mt)
        #pragma unroll
        for (int j = 0; j < 3; ++j)
            facc[mt][j] = (float4v){0.f, 0.f, 0.f, 0.f};

    auto do_gemm2 = [&](int g) {
        #pragma unroll
        for (int ks = 0; ks < 4; ++ks) {
            short8 aG[4];
            #pragma unroll
            for (int mt = 0; mt < 4; ++mt)
                aG[mt] = *(const short8*)&attp[((mt * 4 + ks) << 9) + (lane << 3)];
            #pragma unroll
            for (int j2 = 0; j2 < 3; ++j2) {
                const int tile = 3 * wav + j2;
                short8 bG = *(const short8*)&wop[((tile * 12 + 4 * g + ks) << 9) + (lane << 3)];
                #pragma unroll
                for (int mt = 0; mt < 4; ++mt)
                    facc[mt][j2] = __builtin_amdgcn_mfma_f32_16x16x32_bf16(aG[mt], bG, facc[mt][j2], 0, 0, 0);
            }
        }
    };

    for (int grp = 0; grp < 3; ++grp) {
        const int h = 4 * grp + lh;   // this wave's attention head (global)

        if (grp > 0) do_gemm2(grp - 1);   // fused into the fat phase (reads attp of grp-1)

        // ---------------- GEMM1: qkv for heads 4g..4g+3 ----------------
        float4v acc[3][4];
        #pragma unroll
        for (int n = 0; n < 3; ++n)
            #pragma unroll
            for (int m = 0; m < 4; ++m)
                acc[n][m] = (float4v){0.f, 0.f, 0.f, 0.f};

        int tile_[3], mat_[3], half_[3];
        #pragma unroll
        for (int ntl = 0; ntl < 3; ++ntl) {
            const int part = 3 * mh + ntl;
            mat_[ntl] = part >> 1; half_[ntl] = part & 1;
            tile_[ntl] = mat_[ntl] * 24 + h * 2 + half_[ntl];
        }
        for (int kk = 0; kk < 12; ++kk) {
            short8 aF[4];
            #pragma unroll
            for (int mt = 0; mt < 4; ++mt)
                aF[mt] = *(const short8*)&xnp[(((mt * 12 + kk) << 9)) + (lane << 3)];
            #pragma unroll
            for (int ntl = 0; ntl < 3; ++ntl) {
                short8 bF = *(const short8*)&wqp[((tile_[ntl] * 12 + kk) << 9) + (lane << 3)];
                #pragma unroll
                for (int mt = 0; mt < 4; ++mt)
                    acc[ntl][mt] = __builtin_amdgcn_mfma_f32_16x16x32_bf16(aF[mt], bF, acc[ntl][mt], 0, 0, 0);
            }
        }

        // ---------------- bias prefetch (used after barrier B) ----------------
        float4v bb[2][4];
        #pragma unroll
        for (int j = 0; j < 2; ++j)
            #pragma unroll
            for (int kt = 0; kt < 4; ++kt)
                bb[j][kt] = *(const float4v*)(blutp + ((((h * 4 + (2 * mh + j)) * 4 + kt) << 6) + lane) * 4);

        // ---------------- scatter q,k,v C-frags -> packed operand layouts ----------------
        // C value (token 16mt+4l4+r, dim 16half+lc) of head lh
        #pragma unroll
        for (int ntl = 0; ntl < 3; ++ntl) {
            const int mat = mat_[ntl], half = half_[ntl];
            #pragma unroll
            for (int mt = 0; mt < 4; ++mt) {
                if (mat == 0) {
                    // qp[lh][tt=mt][lane'=(2half+(lc>>3))*16 + 4l4+r][i=lc&7]
                    const int base = ((lh * 4 + mt) << 9) + ((2 * half + (lc >> 3)) << 7) + (lc & 7);
                    #pragma unroll
                    for (int r = 0; r < 4; ++r)
                        qp[base + ((4 * l4 + r) << 3)] = f2bf(acc[ntl][mt][r] * SCALEQ);
                } else if (mat == 1) {
                    const int base = ((lh * 4 + mt) << 9) + ((2 * half + (lc >> 3)) << 7) + (lc & 7);
                    #pragma unroll
                    for (int r = 0; r < 4; ++r)
                        kp[base + ((4 * l4 + r) << 3)] = f2bf(acc[ntl][mt][r]);
                } else {
                    // vp[lh][nt=half][kk2=mt>>1][lane'=(2(mt&1)+(l4>>1))*16+lc][i=4(l4&1)+r] (b64)
                    short4v pk4;
                    #pragma unroll
                    for (int r = 0; r < 4; ++r)
                        pk4[r] = (short)f2bf(acc[ntl][mt][r]);
                    const int addr = (((lh * 2 + half) * 2 + (mt >> 1)) << 9)
                                   + ((((mt & 1) * 2 + (l4 >> 1)) * 16 + lc) << 3)
                                   + ((l4 & 1) << 2);
                    *(short4v*)&vp[addr] = pk4;
                }
            }
        }
        __syncthreads();   // barrier B: q,k,v packed frags visible

        // ---------------- swapped QK^T + bias + softmax (head h, token-tiles 2mh,2mh+1) ----------------
        float sv[2][4][4];
        #pragma unroll
        for (int j = 0; j < 2; ++j) {
            short8 qf = *(const short8*)&qp[((lh * 4 + (2 * mh + j)) << 9) + (lane << 3)];
            #pragma unroll
            for (int kt = 0; kt < 4; ++kt) {
                short8 kf = *(const short8*)&kp[((lh * 4 + kt) << 9) + (lane << 3)];
                float4v sres = __builtin_amdgcn_mfma_f32_16x16x32_bf16(
                    kf, qf, (float4v){0.f, 0.f, 0.f, 0.f}, 0, 0, 0);
                #pragma unroll
                for (int r = 0; r < 4; ++r) sv[j][kt][r] = sres[r];
            }
        }
        unsigned int pk2[2][4][2];
        #pragma unroll
        for (int j = 0; j < 2; ++j) {
            float m = -1e30f;
            #pragma unroll
            for (int kt = 0; kt < 4; ++kt) {
                #pragma unroll
                for (int r = 0; r < 4; ++r) {
                    sv[j][kt][r] += bb[j][kt][r];
                    m = fmaxf(m, sv[j][kt][r]);
                }
            }
            m = fmaxf(m, __shfl_xor(m, 16));
            m = fmaxf(m, __shfl_xor(m, 32));
            float s = 0.f;
            #pragma unroll
            for (int kt = 0; kt < 4; ++kt)
                #pragma unroll
                for (int r = 0; r < 4; ++r) {
                    float pe = __expf(sv[j][kt][r] - m);
                    sv[j][kt][r] = pe; s += pe;
                }
            s += __shfl_xor(s, 16);
            s += __shfl_xor(s, 32);
            const float rinv = 1.f / s;
            #pragma unroll
            for (int kt = 0; kt < 4; ++kt) {
                pk2[j][kt][0] = pack2bf(sv[j][kt][0] * rinv, sv[j][kt][1] * rinv);
                pk2[j][kt][1] = pack2bf(sv[j][kt][2] * rinv, sv[j][kt][3] * rinv);
            }
        }
        // redistribute into PV A-frags: lane(lc,l4) needs P[token 16tt+lc][keys 32kk2+8l4..+7]
        short8 af[2][2];
        {
            const int src0 = lc + 16 * (2 * (l4 & 1));
            const int src1 = src0 + 16;
            const bool hi  = ((l4 >> 1) & 1) != 0;
            #pragma unroll
            for (int j = 0; j < 2; ++j) {
                #pragma unroll
                for (int kk2 = 0; kk2 < 2; ++kk2) {
                    const int ka = 2 * kk2, kb = 2 * kk2 + 1;
                    unsigned int a0a = (unsigned int)__shfl((int)pk2[j][ka][0], src0);
                    unsigned int a0b = (unsigned int)__shfl((int)pk2[j][kb][0], src0);
                    unsigned int a1a = (unsigned int)__shfl((int)pk2[j][ka][1], src0);
                    unsigned int a1b = (unsigned int)__shfl((int)pk2[j][kb][1], src0);
                    unsigned int a2a = (unsigned int)__shfl((int)pk2[j][ka][0], src1);
                    unsigned int a2b = (unsigned int)__shfl((int)pk2[j][kb][0], src1);
                    unsigned int a3a = (unsigned int)__shfl((int)pk2[j][ka][1], src1);
                    unsigned int a3b = (unsigned int)__shfl((int)pk2[j][kb][1], src1);
                    int4v iv;
                    iv[0] = (int)(hi ? a0b : a0a);
                    iv[1] = (int)(hi ? a1b : a1a);
                    iv[2] = (int)(hi ? a2b : a2a);
                    iv[3] = (int)(hi ? a3b : a3a);
                    af[j][kk2] = __builtin_bit_cast(short8, iv);
                }
            }
        }

        // ---------------- PV (token-tiles 2mh..2mh+1, head h) ----------------
        float4v o[2][2];
        #pragma unroll
        for (int j = 0; j < 2; ++j)
            #pragma unroll
            for (int nt = 0; nt < 2; ++nt)
                o[j][nt] = (float4v){0.f, 0.f, 0.f, 0.f};
        #pragma unroll
        for (int kk2 = 0; kk2 < 2; ++kk2) {
            #pragma unroll
            for (int nt = 0; nt < 2; ++nt) {
                short8 vf = *(const short8*)&vp[(((lh * 2 + nt) * 2 + kk2) << 9) + (lane << 3)];
                #pragma unroll
                for (int j = 0; j < 2; ++j)
                    o[j][nt] = __builtin_amdgcn_mfma_f32_16x16x32_bf16(af[j][kk2], vf, o[j][nt], 0, 0, 0);
            }
        }
        // att -> packed A-frags: attp[tt=2mh+j][ks=lh][lane'=(2nt+(lc>>3))*16+4l4+r][i=lc&7]
        #pragma unroll
        for (int j = 0; j < 2; ++j) {
            #pragma unroll
            for (int nt = 0; nt < 2; ++nt) {
                const int base = (((2 * mh + j) * 4 + lh) << 9) + ((2 * nt + (lc >> 3)) << 7) + (lc & 7);
                #pragma unroll
                for (int r = 0; r < 4; ++r)
                    attp[base + ((4 * l4 + r) << 3)] = f2bf(o[j][nt][r]);
            }
        }
        __syncthreads();   // barrier D: attp visible (GEMM2 of this grp runs next iteration / after loop)
    }
    do_gemm2(2);

    // ---------------- epilogue: facc + b_out -> direct f32 global stores ----------------
    {
        float* ob = out + b * (NTOK * CCH);
        #pragma unroll
        for (int mt = 0; mt < 4; ++mt) {
            #pragma unroll
            for (int j2 = 0; j2 < 3; ++j2) {
                const int c = 16 * (3 * wav + j2) + lc;
                const float bo = b_out[c];
                #pragma unroll
                for (int r = 0; r < 4; ++r)
                    ob[(16 * mt + 4 * l4 + r) * CCH + c] = facc[mt][j2][r] + bo;
            }
        }
    }
}

extern "C" void kernel_launch(void* const* d_in, const int* in_sizes, int n_in,
                              void* d_out, int out_size, void* d_ws, size_t ws_size,
                              hipStream_t stream) {
    const float* x     = (const float*)d_in[0];
    const float* ln_g  = (const float*)d_in[1];
    const float* ln_b  = (const float*)d_in[2];
    const float* w_qkv = (const float*)d_in[3];
    const float* w_out = (const float*)d_in[4];
    const float* b_out = (const float*)d_in[5];
    const float* btab  = (const float*)d_in[6];
    const int*   ridx  = (const int*)d_in[7];
    float*       out   = (float*)d_out;

    unsigned short* wqp   = (unsigned short*)d_ws;
    unsigned short* wop   = wqp + WQP_ELEMS;
    float*          blutp = (float*)(wop + WOP_ELEMS);   // byte offset 1179648, 16B-aligned

    prep_kernel<<<512, 256, 0, stream>>>(w_qkv, w_out, btab, ridx, wqp, wop, blutp);
    fused_win_mha<<<2048, 512, 0, stream>>>(x, ln_g, ln_b, b_out, wqp, wop, blutp, out);
}